// Round 11
// baseline (355.208 us; speedup 1.0000x reference)
//
#include <hip/hip_runtime.h>
#include <hip/hip_fp16.h>

#define N_NODES  100000
#define N_EDGES  1600000
#define N_GRAPHS 64

#define BINSH  8
#define NBIN   392          // ceil(100000 / 256)
#define BINCAP 8192         // Poisson(4096) max ~4.5K; ~2x headroom
#define EPB    2048         // edges per block in k_binA

__device__ __forceinline__ float lrelu(float v) { return v > 0.f ? v : 0.2f * v; }
__device__ __forceinline__ float elu_f(float v) { return v > 0.f ? v : __expf(v) - 1.f; }
__device__ __forceinline__ float rdlane_f(float v, int lane) {
    return __int_as_float(__builtin_amdgcn_readlane(__float_as_int(v), lane));
}

// ---- Pass A: coarse-bin edges (dst>>8) into per-bin regions, coalesced runs.
// int4 edge loads (4 edges/thread) + 2-barrier wave scan.
__global__ __launch_bounds__(512) void k_binA(
    const int* __restrict__ src, const int* __restrict__ dst,
    const int* __restrict__ batch, int* __restrict__ gbin_cursor,
    int* __restrict__ cnt, int2* __restrict__ binned) {
    __shared__ int hist[NBIN], lexcl[NBIN], runbase[NBIN], lcur[NBIN];
    __shared__ int wpart[8];
    __shared__ int gh[N_GRAPHS];
    __shared__ int2 stage[EPB];
    int t = threadIdx.x;
    int e0 = blockIdx.x * EPB;
    for (int b = t; b < NBIN; b += 512) hist[b] = 0;
    if (t < N_GRAPHS) gh[t] = 0;
    __syncthreads();
    int nid = blockIdx.x * 512 + t;   // 782*512 >= N_NODES
    if (nid < N_NODES) atomicAdd(&gh[batch[nid]], 1);
    int e = 4 * t;                    // block-local edge base
    int4 dv = make_int4(0, 0, 0, 0), sv = make_int4(0, 0, 0, 0);
    bool full = (e0 + e + 3 < N_EDGES);
    if (full) {
        dv = *(const int4*)(dst + e0 + e);
        sv = *(const int4*)(src + e0 + e);
        atomicAdd(&hist[dv.x >> BINSH], 1);
        atomicAdd(&hist[dv.y >> BINSH], 1);
        atomicAdd(&hist[dv.z >> BINSH], 1);
        atomicAdd(&hist[dv.w >> BINSH], 1);
    } else {
        for (int k = 0; k < 4; ++k)
            if (e0 + e + k < N_EDGES) atomicAdd(&hist[dst[e0 + e + k] >> BINSH], 1);
    }
    __syncthreads();
    // wave-level exclusive scan over NBIN histogram slots
    int v = (t < NBIN) ? hist[t] : 0;
    int x = v;
#pragma unroll
    for (int d = 1; d < 64; d <<= 1) {
        int y = __shfl_up(x, d, 64);
        if ((t & 63) >= d) x += y;
    }
    if ((t & 63) == 63) wpart[t >> 6] = x;
    __syncthreads();
    if (t == 0) {
        int a = 0;
        for (int w = 0; w < 8; ++w) { int q = wpart[w]; wpart[w] = a; a += q; }
    }
    __syncthreads();
    int excl = x - v + wpart[t >> 6];
    if (t < NBIN) { lexcl[t] = excl; lcur[t] = excl; }
    __syncthreads();
    if (t < NBIN && v > 0) runbase[t] = atomicAdd(&gbin_cursor[t], v);
    if (t < N_GRAPHS && gh[t]) atomicAdd(&cnt[t], gh[t]);
    __syncthreads();
    if (full) {
        int p;
        p = atomicAdd(&lcur[dv.x >> BINSH], 1); stage[p] = make_int2(sv.x, dv.x);
        p = atomicAdd(&lcur[dv.y >> BINSH], 1); stage[p] = make_int2(sv.y, dv.y);
        p = atomicAdd(&lcur[dv.z >> BINSH], 1); stage[p] = make_int2(sv.z, dv.z);
        p = atomicAdd(&lcur[dv.w >> BINSH], 1); stage[p] = make_int2(sv.w, dv.w);
    } else {
        for (int k = 0; k < 4; ++k) {
            if (e0 + e + k < N_EDGES) {
                int d = dst[e0 + e + k];
                int p = atomicAdd(&lcur[d >> BINSH], 1);
                stage[p] = make_int2(src[e0 + e + k], d);
            }
        }
    }
    __syncthreads();
    int m = N_EDGES - e0;
    if (m > EPB) m = EPB;
    for (int i = 4 * t; i < 4 * t + 4 && i < m; ++i) {
        int2 pr = stage[i];
        int b = pr.y >> BINSH;
        binned[(size_t)b * BINCAP + runbase[b] + (i - lexcl[b])] = pr;
    }
}

// ---- Pass B: per-bin counting sort over 256 local nodes -> off[] + csr[].
// (src-bucket sub-key removed: R9 proved it neutral; 256-key scan is cheaper.)
__global__ __launch_bounds__(1024) void k_binB(
    const int2* __restrict__ binned, const int* __restrict__ gbin_cursor,
    int* __restrict__ off, int* __restrict__ csr) {
    __shared__ int hist[256];
    __shared__ int wpart[4];
    __shared__ int s_ebase;
    int b = blockIdx.x, t = threadIdx.x;
    int count = gbin_cursor[b];
    int node0 = b << BINSH;
    const int2* my = binned + (size_t)b * BINCAP;
    if (t == 0) s_ebase = 0;
    if (t < 256) hist[t] = 0;
    __syncthreads();
    if (t < b) atomicAdd(&s_ebase, gbin_cursor[t]);  // t<b<NBIN -> valid
    for (int i = t; i < count; i += 1024) atomicAdd(&hist[my[i].y - node0], 1);
    __syncthreads();
    // exclusive scan over 256 keys: 4 waves + partials
    int v = (t < 256) ? hist[t] : 0;
    int x = v;
#pragma unroll
    for (int d = 1; d < 64; d <<= 1) {
        int y = __shfl_up(x, d, 64);
        if ((t & 63) >= d) x += y;
    }
    if (t < 256 && (t & 63) == 63) wpart[t >> 6] = x;
    __syncthreads();
    if (t == 0) {
        int a = 0;
        for (int w = 0; w < 4; ++w) { int q = wpart[w]; wpart[w] = a; a += q; }
    }
    __syncthreads();
    int ebase = s_ebase;
    int excl = x - v + ((t < 256) ? wpart[t >> 6] : 0);
    if (t < 256) {
        int n = node0 + t;
        if (n < N_NODES) off[n] = ebase + excl;
    }
    if (b == 0 && t == 0) off[N_NODES] = N_EDGES;
    __syncthreads();
    if (t < 256) hist[t] = excl;  // becomes the local cursor
    __syncthreads();
    for (int i = t; i < count; i += 1024) {
        int2 pr = my[i];
        int p = atomicAdd(&hist[pr.y - node0], 1);
        csr[ebase + p] = pr.x;
    }
}

// ---- Fused Layer1 + GEMM + attention epilogue. Block = 256, 32 nodes/block.
// Phase 2 loop-interchanged: k2 outer, 8 nodes inner -> each smW4 entry read
// ONCE per wave (32 ds_read_b128 vs 256), a-values hoisted into av[8].
__global__ __launch_bounds__(256) void k_l1gemm(
    const float* __restrict__ x, const float* __restrict__ W1,
    const float* __restrict__ as1, const float* __restrict__ ad1,
    const float* __restrict__ b1, const float* __restrict__ W2,
    const float* __restrict__ as2, const float* __restrict__ ad2,
    const int* __restrict__ off, const int* __restrict__ csr,
    __half2* __restrict__ h2p, float2* __restrict__ ap, float2* __restrict__ dp) {
    __shared__ float4 smW4[32 * 64];   // {W2[2k][l], W2[2k][64+l], W2[2k+1][l], W2[2k+1][64+l]}
    __shared__ float smS1[32][8];
    __shared__ float smws[8], smwd[8];
    int t = threadIdx.x;
    for (int idx = t; idx < 2048; idx += 256) {
        int k2 = idx >> 6, ll = idx & 63;
        smW4[idx] = make_float4(W2[(2 * k2) * 128 + ll], W2[(2 * k2) * 128 + 64 + ll],
                                W2[(2 * k2 + 1) * 128 + ll], W2[(2 * k2 + 1) * 128 + 64 + ll]);
    }
    if (t < 8) {
        float s = 0.f, d = 0.f;
        for (int c = 0; c < 8; ++c) {
            float w = W1[t * 8 + c];
            s += w * as1[t * 8 + c];
            d += w * ad1[t * 8 + c];
        }
        smws[t] = s;
        smwd[t] = d;
    }
    __syncthreads();

    // ---- phase 1: layer 1 for 32 nodes (16 lanes each, 2 passes)
    {
        int c = t & 15;
        float ws[8], wd[8];
#pragma unroll
        for (int h = 0; h < 8; ++h) { ws[h] = smws[h]; wd[h] = smwd[h]; }
        for (int p = 0; p < 2; ++p) {
            int nl = p * 16 + (t >> 4);
            int n = blockIdx.x * 32 + nl;   // grid exact: 3125*32 == N_NODES
            float xn = x[n];
            float num[8], den[8];
#pragma unroll
            for (int h = 0; h < 8; ++h) { num[h] = 0.f; den[h] = 0.f; }
            if (c == 0) {  // self loop
#pragma unroll
                for (int h = 0; h < 8; ++h) {
                    float w = __expf(lrelu(xn * ws[h] + xn * wd[h]));
                    den[h] = w;
                    num[h] = w * xn;
                }
            }
            int bo = off[n], e = off[n + 1];
            for (int i = bo + c; i < e; i += 16) {
                int s = csr[i];
                float xs = x[s];
#pragma unroll
                for (int h = 0; h < 8; ++h) {
                    float w = __expf(lrelu(xs * ws[h] + xn * wd[h]));
                    den[h] += w;
                    num[h] += w * xs;
                }
            }
#pragma unroll
            for (int d = 1; d < 16; d <<= 1) {
#pragma unroll
                for (int h = 0; h < 8; ++h) {
                    num[h] += __shfl_xor(num[h], d, 64);
                    den[h] += __shfl_xor(den[h], d, 64);
                }
            }
            if (c == 0) {
#pragma unroll
                for (int h = 0; h < 8; ++h) smS1[nl][h] = num[h] / den[h];
            }
        }
    }
    __syncthreads();

    // ---- phase 2: gemm for 8 nodes per wave, k2-outer
    int wid = t >> 6, l = t & 63;
    float w1l = W1[l], b1l = b1[l];
    float av[8], acc0[8], acc1[8];
#pragma unroll
    for (int q = 0; q < 8; ++q) {
        av[q] = elu_f(smS1[wid * 8 + q][l >> 3] * w1l + b1l);
        acc0[q] = 0.f;
        acc1[q] = 0.f;
    }
#pragma unroll
    for (int k2 = 0; k2 < 32; ++k2) {
        float4 wv = smW4[k2 * 64 + l];   // one LDS read serves all 8 nodes
#pragma unroll
        for (int q = 0; q < 8; ++q) {
            float a0 = rdlane_f(av[q], 2 * k2);
            float a1 = rdlane_f(av[q], 2 * k2 + 1);
            acc0[q] += a0 * wv.x + a1 * wv.z;
            acc1[q] += a0 * wv.y + a1 * wv.w;
        }
    }
    float asA = as2[l], asB = as2[64 + l], adA = ad2[l], adB = ad2[64 + l];
#pragma unroll
    for (int q = 0; q < 8; ++q) {
        int n = blockIdx.x * 32 + wid * 8 + q;
        h2p[n * 64 + l] = __floats2half2_rn(acc0[q], acc1[q]);

        float pSA = acc0[q] * asA;
        float pSB = acc1[q] * asB;
        float pDA = acc0[q] * adA;
        float pDB = acc1[q] * adB;
#pragma unroll
        for (int d = 1; d < 16; d <<= 1) {
            pSA += __shfl_xor(pSA, d, 64);
            pSB += __shfl_xor(pSB, d, 64);
            pDA += __shfl_xor(pDA, d, 64);
            pDB += __shfl_xor(pDB, d, 64);
        }
        if ((l & 15) == 0) {
            int h = l >> 4;
            ap[n * 4 + h] = make_float2(pSA, pSB);
            dp[n * 4 + h] = make_float2(pDA, pDB);
        }
    }
}

// ---- Layer 2 aggregation: frozen at the R10 structure (best known: ~111us,
// pinned by the random-gather path at ~2.4 TB/s — R7/R8/R9 experiments show
// concurrency, unroll, and locality knobs are all neutral-to-negative).
__global__ __launch_bounds__(256, 8) void k_layer2(
    const __half2* __restrict__ h2p, const float2* __restrict__ ap,
    const float2* __restrict__ dp, const int* __restrict__ off,
    const int* __restrict__ csr, const int* __restrict__ batch,
    float* __restrict__ pool) {
    __shared__ float smv[4][16];
    __shared__ int smg[4];
    const float* apf = (const float*)ap;   // flat: node*8 + 2*(h&3) + (h>>2)
    const float* dpf = (const float*)dp;
    int t = threadIdx.x;
    int wid = t >> 6, l = t & 63;
    int n = blockIdx.x * 4 + wid;  // grid exact: 25000*4 == N_NODES
    int hA = l >> 4;               // channel-group head
    int hh = l & 7;                // weight-phase head
    int j8 = l >> 3;               // weight-phase edge slot
    int fidx = 2 * (hh & 3) + (hh >> 2);
    float dn = dpf[n * 8 + fidx];  // adst[n][hh]

    // self loop (heads hA, hA+4)
    float2 ad = dp[n * 4 + hA];
    float2 an = ap[n * 4 + hA];
    float wA = __expf(lrelu(an.x + ad.x));
    float wB = __expf(lrelu(an.y + ad.y));
    float2 hn = __half22float2(h2p[n * 64 + l]);
    float accA = wA * hn.x, accB = wB * hn.y;
    float denTA = wA, denTB = wB;
    float wsum = 0.f;

    int b = off[n];
    int deg = off[n + 1] - b;
    for (int base = 0; base < deg; base += 64) {
        int rem = deg - base;
        if (rem > 64) rem = 64;
        int sl = (l < rem) ? csr[b + base + l] : 0;  // one coalesced load / chunk
        int g = 0;
        for (; g + 8 <= rem; g += 8) {
            // weight phase: 64 distinct (edge,head) -> one exp
            int sg = __shfl(sl, g + j8, 64);
            float w = __expf(lrelu(apf[sg * 8 + fidx] + dn));
            wsum += w;
#pragma unroll
            for (int j2 = 0; j2 < 8; ++j2) {
                int s = __builtin_amdgcn_readlane(sl, g + j2);   // SGPR src id
                float wa = __shfl(w, j2 * 8 + hA, 64);
                float wb = __shfl(w, j2 * 8 + hA + 4, 64);
                float2 gg = __half22float2(h2p[s * 64 + l]);
                accA = fmaf(wa, gg.x, accA);
                accB = fmaf(wb, gg.y, accB);
            }
        }
        if (g < rem) {  // partial group (1..7 edges)
            int cnt = rem - g;
            int jj = (j8 < cnt) ? j8 : 0;
            int sg = __shfl(sl, g + jj, 64);
            float w = (j8 < cnt) ? __expf(lrelu(apf[sg * 8 + fidx] + dn)) : 0.f;
            wsum += w;
            for (int j2 = 0; j2 < cnt; ++j2) {
                int s = __builtin_amdgcn_readlane(sl, g + j2);
                float wa = __shfl(w, j2 * 8 + hA, 64);
                float wb = __shfl(w, j2 * 8 + hA + 4, 64);
                float2 gg = __half22float2(h2p[s * 64 + l]);
                accA = fmaf(wa, gg.x, accA);
                accB = fmaf(wb, gg.y, accB);
            }
        }
    }
    // den[h] = sum over edge slots (lanes h, h+8, ..., h+56)
    wsum += __shfl_xor(wsum, 8, 64);
    wsum += __shfl_xor(wsum, 16, 64);
    wsum += __shfl_xor(wsum, 32, 64);
    float denA = denTA + __shfl(wsum, hA, 64);
    float denB = denTB + __shfl(wsum, hA + 4, 64);

    float v = accA / denA + accB / denB;
    v += __shfl_xor(v, 16, 64);
    v += __shfl_xor(v, 32, 64);
    v *= 0.125f;  // mean over 8 heads
    if (l < 16) smv[wid][l] = v;
    if (l == 0) smg[wid] = batch[n];
    __syncthreads();
    if (t < 64) {
        int w = t >> 4, c = t & 15;
        int g = smg[w];
        bool leader = true;
        for (int w2 = 0; w2 < w; ++w2)
            if (smg[w2] == g) { leader = false; break; }
        if (leader) {
            float s = smv[w][c];
            for (int w2 = w + 1; w2 < 4; ++w2)
                if (smg[w2] == g) s += smv[w2][c];
            atomicAdd(&pool[g * 16 + c], s);
        }
    }
}

// ---- final: pooled mean (+b2) @ Wfc + bfc -> [64,4]
__global__ void k_final(const float* __restrict__ pool, const int* __restrict__ cnt,
                        const float* __restrict__ b2, const float* __restrict__ Wfc,
                        const float* __restrict__ bfc, float* __restrict__ out) {
    int t = threadIdx.x;
    int g = t >> 2, k = t & 3;
    float c = (float)(cnt[g] > 0 ? cnt[g] : 1);
    float acc = bfc[k];
#pragma unroll
    for (int ci = 0; ci < 16; ++ci)
        acc += (pool[g * 16 + ci] / c + b2[ci]) * Wfc[ci * 4 + k];
    out[g * 4 + k] = acc;
}

extern "C" void kernel_launch(void* const* d_in, const int* in_sizes, int n_in,
                              void* d_out, int out_size, void* d_ws, size_t ws_size,
                              hipStream_t stream) {
    const float* x   = (const float*)d_in[0];
    const float* W1  = (const float*)d_in[1];
    const float* as1 = (const float*)d_in[2];
    const float* ad1 = (const float*)d_in[3];
    const float* b1  = (const float*)d_in[4];
    const float* W2  = (const float*)d_in[5];
    const float* as2 = (const float*)d_in[6];
    const float* ad2 = (const float*)d_in[7];
    const float* b2  = (const float*)d_in[8];
    const float* Wfc = (const float*)d_in[9];
    const float* bfc = (const float*)d_in[10];
    const int* ei    = (const int*)d_in[11];
    const int* batch = (const int*)d_in[12];
    const int* srcv  = ei;             // edge_index[0]
    const int* dstv  = ei + N_EDGES;   // edge_index[1]

    char* ws = (char*)d_ws;
    size_t o = 0;
    auto alloc = [&](size_t bytes) {
        void* p = ws + o;
        o += (bytes + 255) & ~(size_t)255;
        return p;
    };
    // zero-region first (one memset): cnt, pool, gbin_cursor
    int*    cnt     = (int*)alloc(64 * 4);
    float*  pool    = (float*)alloc(64 * 16 * 4);
    int*    gbin    = (int*)alloc(NBIN * 4);
    size_t  zbytes  = o;
    int*    off     = (int*)alloc((size_t)(N_NODES + 1) * 4);
    int*    csr     = (int*)alloc((size_t)N_EDGES * 4);
    // union region: binned (CSR build only) aliases h2p/ap/dp (l1gemm onward)
    // binned: 392*8192*8 = 25.69 MB <= 32.0 MB region
    char*   ubase   = (char*)alloc((size_t)N_NODES * 64 * 4 + (size_t)N_NODES * 4 * 8 * 2);
    int2*   binned  = (int2*)ubase;
    __half2* h2p    = (__half2*)ubase;
    float2* ap      = (float2*)(ubase + (size_t)N_NODES * 64 * 4);
    float2* dp      = (float2*)(ubase + (size_t)N_NODES * 64 * 4 + (size_t)N_NODES * 4 * 8);

    hipMemsetAsync(d_ws, 0, zbytes, stream);

    int nbA = (N_EDGES + EPB - 1) / EPB;   // 782

    k_binA<<<nbA, 512, 0, stream>>>(srcv, dstv, batch, gbin, cnt, binned);
    k_binB<<<NBIN, 1024, 0, stream>>>(binned, gbin, off, csr);
    k_l1gemm<<<N_NODES / 32, 256, 0, stream>>>(x, W1, as1, ad1, b1, W2, as2, ad2,
                                               off, csr, h2p, ap, dp);
    k_layer2<<<N_NODES / 4, 256, 0, stream>>>(h2p, ap, dp, off, csr, batch, pool);
    k_final<<<1, 256, 0, stream>>>(pool, cnt, b2, Wfc, bfc, (float*)d_out);
}

// Round 12
// 306.313 us; speedup vs baseline: 1.1596x; 1.1596x over previous
//
#include <hip/hip_runtime.h>
#include <hip/hip_fp16.h>

#define N_NODES  100000
#define N_EDGES  1600000
#define N_GRAPHS 64

#define BINSH  8
#define NBIN   392          // ceil(100000 / 256)
#define BINCAP 8192         // Poisson(4096) max ~4.5K; ~2x headroom
#define EPB    2048         // edges per block in k_binA

__device__ __forceinline__ float lrelu(float v) { return v > 0.f ? v : 0.2f * v; }
__device__ __forceinline__ float elu_f(float v) { return v > 0.f ? v : __expf(v) - 1.f; }
__device__ __forceinline__ float rdlane_f(float v, int lane) {
    return __int_as_float(__builtin_amdgcn_readlane(__float_as_int(v), lane));
}

// ---- Pass A: coarse-bin edges (dst>>8) into per-bin regions, coalesced runs.
__global__ __launch_bounds__(512) void k_binA(
    const int* __restrict__ src, const int* __restrict__ dst,
    const int* __restrict__ batch, int* __restrict__ gbin_cursor,
    int* __restrict__ cnt, int2* __restrict__ binned) {
    __shared__ int hist[NBIN], lexcl[NBIN], runbase[NBIN], lcur[NBIN];
    __shared__ int wpart[8];
    __shared__ int gh[N_GRAPHS];
    __shared__ int2 stage[EPB];
    int t = threadIdx.x;
    int e0 = blockIdx.x * EPB;
    for (int b = t; b < NBIN; b += 512) hist[b] = 0;
    if (t < N_GRAPHS) gh[t] = 0;
    __syncthreads();
    int nid = blockIdx.x * 512 + t;   // 782*512 >= N_NODES
    if (nid < N_NODES) atomicAdd(&gh[batch[nid]], 1);
    int e = 4 * t;                    // block-local edge base
    int4 dv = make_int4(0, 0, 0, 0), sv = make_int4(0, 0, 0, 0);
    bool full = (e0 + e + 3 < N_EDGES);
    if (full) {
        dv = *(const int4*)(dst + e0 + e);
        sv = *(const int4*)(src + e0 + e);
        atomicAdd(&hist[dv.x >> BINSH], 1);
        atomicAdd(&hist[dv.y >> BINSH], 1);
        atomicAdd(&hist[dv.z >> BINSH], 1);
        atomicAdd(&hist[dv.w >> BINSH], 1);
    } else {
        for (int k = 0; k < 4; ++k)
            if (e0 + e + k < N_EDGES) atomicAdd(&hist[dst[e0 + e + k] >> BINSH], 1);
    }
    __syncthreads();
    // wave-level exclusive scan over NBIN histogram slots
    int v = (t < NBIN) ? hist[t] : 0;
    int x = v;
#pragma unroll
    for (int d = 1; d < 64; d <<= 1) {
        int y = __shfl_up(x, d, 64);
        if ((t & 63) >= d) x += y;
    }
    if ((t & 63) == 63) wpart[t >> 6] = x;
    __syncthreads();
    if (t == 0) {
        int a = 0;
        for (int w = 0; w < 8; ++w) { int q = wpart[w]; wpart[w] = a; a += q; }
    }
    __syncthreads();
    int excl = x - v + wpart[t >> 6];
    if (t < NBIN) { lexcl[t] = excl; lcur[t] = excl; }
    __syncthreads();
    if (t < NBIN && v > 0) runbase[t] = atomicAdd(&gbin_cursor[t], v);
    if (t < N_GRAPHS && gh[t]) atomicAdd(&cnt[t], gh[t]);
    __syncthreads();
    if (full) {
        int p;
        p = atomicAdd(&lcur[dv.x >> BINSH], 1); stage[p] = make_int2(sv.x, dv.x);
        p = atomicAdd(&lcur[dv.y >> BINSH], 1); stage[p] = make_int2(sv.y, dv.y);
        p = atomicAdd(&lcur[dv.z >> BINSH], 1); stage[p] = make_int2(sv.z, dv.z);
        p = atomicAdd(&lcur[dv.w >> BINSH], 1); stage[p] = make_int2(sv.w, dv.w);
    } else {
        for (int k = 0; k < 4; ++k) {
            if (e0 + e + k < N_EDGES) {
                int d = dst[e0 + e + k];
                int p = atomicAdd(&lcur[d >> BINSH], 1);
                stage[p] = make_int2(src[e0 + e + k], d);
            }
        }
    }
    __syncthreads();
    int m = N_EDGES - e0;
    if (m > EPB) m = EPB;
    for (int i = 4 * t; i < 4 * t + 4 && i < m; ++i) {
        int2 pr = stage[i];
        int b = pr.y >> BINSH;
        binned[(size_t)b * BINCAP + runbase[b] + (i - lexcl[b])] = pr;
    }
}

// ---- Pass B: per-bin counting sort over 256 local nodes -> off[] + csr[].
__global__ __launch_bounds__(1024) void k_binB(
    const int2* __restrict__ binned, const int* __restrict__ gbin_cursor,
    int* __restrict__ off, int* __restrict__ csr) {
    __shared__ int hist[256];
    __shared__ int wpart[4];
    __shared__ int s_ebase;
    int b = blockIdx.x, t = threadIdx.x;
    int count = gbin_cursor[b];
    int node0 = b << BINSH;
    const int2* my = binned + (size_t)b * BINCAP;
    if (t == 0) s_ebase = 0;
    if (t < 256) hist[t] = 0;
    __syncthreads();
    if (t < b) atomicAdd(&s_ebase, gbin_cursor[t]);  // t<b<NBIN -> valid
    for (int i = t; i < count; i += 1024) atomicAdd(&hist[my[i].y - node0], 1);
    __syncthreads();
    // exclusive scan over 256 keys: 4 waves + partials
    int v = (t < 256) ? hist[t] : 0;
    int x = v;
#pragma unroll
    for (int d = 1; d < 64; d <<= 1) {
        int y = __shfl_up(x, d, 64);
        if ((t & 63) >= d) x += y;
    }
    if (t < 256 && (t & 63) == 63) wpart[t >> 6] = x;
    __syncthreads();
    if (t == 0) {
        int a = 0;
        for (int w = 0; w < 4; ++w) { int q = wpart[w]; wpart[w] = a; a += q; }
    }
    __syncthreads();
    int ebase = s_ebase;
    int excl = x - v + ((t < 256) ? wpart[t >> 6] : 0);
    if (t < 256) {
        int n = node0 + t;
        if (n < N_NODES) off[n] = ebase + excl;
    }
    if (b == 0 && t == 0) off[N_NODES] = N_EDGES;
    __syncthreads();
    if (t < 256) hist[t] = excl;  // becomes the local cursor
    __syncthreads();
    for (int i = t; i < count; i += 1024) {
        int2 pr = my[i];
        int p = atomicAdd(&hist[pr.y - node0], 1);
        csr[ebase + p] = pr.x;
    }
}

// ---- Fused Layer1 + GEMM + attention epilogue. Block = 256, 32 nodes/block.
// Phase 2: node-PAIR blocking — one smW4 read serves 2 nodes (halves the
// ~60us LDS-pipe term of the q-outer form) while keeping register pressure
// near R10 levels (the 8-node interchange hit VGPR 92 / 20% occupancy).
__global__ __launch_bounds__(256) void k_l1gemm(
    const float* __restrict__ x, const float* __restrict__ W1,
    const float* __restrict__ as1, const float* __restrict__ ad1,
    const float* __restrict__ b1, const float* __restrict__ W2,
    const float* __restrict__ as2, const float* __restrict__ ad2,
    const int* __restrict__ off, const int* __restrict__ csr,
    __half2* __restrict__ h2p, float2* __restrict__ ap, float2* __restrict__ dp) {
    __shared__ float4 smW4[32 * 64];   // {W2[2k][l], W2[2k][64+l], W2[2k+1][l], W2[2k+1][64+l]}
    __shared__ float smS1[32][8];
    __shared__ float smws[8], smwd[8];
    int t = threadIdx.x;
    for (int idx = t; idx < 2048; idx += 256) {
        int k2 = idx >> 6, ll = idx & 63;
        smW4[idx] = make_float4(W2[(2 * k2) * 128 + ll], W2[(2 * k2) * 128 + 64 + ll],
                                W2[(2 * k2 + 1) * 128 + ll], W2[(2 * k2 + 1) * 128 + 64 + ll]);
    }
    if (t < 8) {
        float s = 0.f, d = 0.f;
        for (int c = 0; c < 8; ++c) {
            float w = W1[t * 8 + c];
            s += w * as1[t * 8 + c];
            d += w * ad1[t * 8 + c];
        }
        smws[t] = s;
        smwd[t] = d;
    }
    __syncthreads();

    // ---- phase 1: layer 1 for 32 nodes (16 lanes each, 2 passes)
    {
        int c = t & 15;
        float ws[8], wd[8];
#pragma unroll
        for (int h = 0; h < 8; ++h) { ws[h] = smws[h]; wd[h] = smwd[h]; }
        for (int p = 0; p < 2; ++p) {
            int nl = p * 16 + (t >> 4);
            int n = blockIdx.x * 32 + nl;   // grid exact: 3125*32 == N_NODES
            float xn = x[n];
            float num[8], den[8];
#pragma unroll
            for (int h = 0; h < 8; ++h) { num[h] = 0.f; den[h] = 0.f; }
            if (c == 0) {  // self loop
#pragma unroll
                for (int h = 0; h < 8; ++h) {
                    float w = __expf(lrelu(xn * ws[h] + xn * wd[h]));
                    den[h] = w;
                    num[h] = w * xn;
                }
            }
            int bo = off[n], e = off[n + 1];
            for (int i = bo + c; i < e; i += 16) {
                int s = csr[i];
                float xs = x[s];
#pragma unroll
                for (int h = 0; h < 8; ++h) {
                    float w = __expf(lrelu(xs * ws[h] + xn * wd[h]));
                    den[h] += w;
                    num[h] += w * xs;
                }
            }
#pragma unroll
            for (int d = 1; d < 16; d <<= 1) {
#pragma unroll
                for (int h = 0; h < 8; ++h) {
                    num[h] += __shfl_xor(num[h], d, 64);
                    den[h] += __shfl_xor(den[h], d, 64);
                }
            }
            if (c == 0) {
#pragma unroll
                for (int h = 0; h < 8; ++h) smS1[nl][h] = num[h] / den[h];
            }
        }
    }
    __syncthreads();

    // ---- phase 2: gemm, 8 nodes per wave in 4 sequential PAIRS
    int wid = t >> 6, l = t & 63;
    float w1l = W1[l], b1l = b1[l];
    float asA = as2[l], asB = as2[64 + l], adA = ad2[l], adB = ad2[64 + l];
    for (int qp = 0; qp < 4; ++qp) {
        int nl0 = wid * 8 + 2 * qp;
        float a0v = elu_f(smS1[nl0][l >> 3] * w1l + b1l);
        float a1v = elu_f(smS1[nl0 + 1][l >> 3] * w1l + b1l);
        float acc00 = 0.f, acc01 = 0.f, acc10 = 0.f, acc11 = 0.f;
#pragma unroll
        for (int k2 = 0; k2 < 32; ++k2) {
            float4 wv = smW4[k2 * 64 + l];   // one LDS read serves both nodes
            float x0 = rdlane_f(a0v, 2 * k2);
            float x1 = rdlane_f(a0v, 2 * k2 + 1);
            float y0 = rdlane_f(a1v, 2 * k2);
            float y1 = rdlane_f(a1v, 2 * k2 + 1);
            acc00 += x0 * wv.x + x1 * wv.z;
            acc01 += x0 * wv.y + x1 * wv.w;
            acc10 += y0 * wv.x + y1 * wv.z;
            acc11 += y0 * wv.y + y1 * wv.w;
        }
#pragma unroll
        for (int u = 0; u < 2; ++u) {
            float acc0 = u ? acc10 : acc00;
            float acc1 = u ? acc11 : acc01;
            int n = blockIdx.x * 32 + nl0 + u;
            h2p[n * 64 + l] = __floats2half2_rn(acc0, acc1);

            float pSA = acc0 * asA;
            float pSB = acc1 * asB;
            float pDA = acc0 * adA;
            float pDB = acc1 * adB;
#pragma unroll
            for (int d = 1; d < 16; d <<= 1) {
                pSA += __shfl_xor(pSA, d, 64);
                pSB += __shfl_xor(pSB, d, 64);
                pDA += __shfl_xor(pDA, d, 64);
                pDB += __shfl_xor(pDB, d, 64);
            }
            if ((l & 15) == 0) {
                int h = l >> 4;
                ap[n * 4 + h] = make_float2(pSA, pSB);
                dp[n * 4 + h] = make_float2(pDA, pDB);
            }
        }
    }
}

// ---- Layer 2 aggregation: frozen at the R10 structure (best known: ~111us,
// pinned by the random-gather path at ~2.4 TB/s).
__global__ __launch_bounds__(256, 8) void k_layer2(
    const __half2* __restrict__ h2p, const float2* __restrict__ ap,
    const float2* __restrict__ dp, const int* __restrict__ off,
    const int* __restrict__ csr, const int* __restrict__ batch,
    float* __restrict__ pool) {
    __shared__ float smv[4][16];
    __shared__ int smg[4];
    const float* apf = (const float*)ap;   // flat: node*8 + 2*(h&3) + (h>>2)
    const float* dpf = (const float*)dp;
    int t = threadIdx.x;
    int wid = t >> 6, l = t & 63;
    int n = blockIdx.x * 4 + wid;  // grid exact: 25000*4 == N_NODES
    int hA = l >> 4;               // channel-group head
    int hh = l & 7;                // weight-phase head
    int j8 = l >> 3;               // weight-phase edge slot
    int fidx = 2 * (hh & 3) + (hh >> 2);
    float dn = dpf[n * 8 + fidx];  // adst[n][hh]

    // self loop (heads hA, hA+4)
    float2 ad = dp[n * 4 + hA];
    float2 an = ap[n * 4 + hA];
    float wA = __expf(lrelu(an.x + ad.x));
    float wB = __expf(lrelu(an.y + ad.y));
    float2 hn = __half22float2(h2p[n * 64 + l]);
    float accA = wA * hn.x, accB = wB * hn.y;
    float denTA = wA, denTB = wB;
    float wsum = 0.f;

    int b = off[n];
    int deg = off[n + 1] - b;
    for (int base = 0; base < deg; base += 64) {
        int rem = deg - base;
        if (rem > 64) rem = 64;
        int sl = (l < rem) ? csr[b + base + l] : 0;  // one coalesced load / chunk
        int g = 0;
        for (; g + 8 <= rem; g += 8) {
            // weight phase: 64 distinct (edge,head) -> one exp
            int sg = __shfl(sl, g + j8, 64);
            float w = __expf(lrelu(apf[sg * 8 + fidx] + dn));
            wsum += w;
#pragma unroll
            for (int j2 = 0; j2 < 8; ++j2) {
                int s = __builtin_amdgcn_readlane(sl, g + j2);   // SGPR src id
                float wa = __shfl(w, j2 * 8 + hA, 64);
                float wb = __shfl(w, j2 * 8 + hA + 4, 64);
                float2 gg = __half22float2(h2p[s * 64 + l]);
                accA = fmaf(wa, gg.x, accA);
                accB = fmaf(wb, gg.y, accB);
            }
        }
        if (g < rem) {  // partial group (1..7 edges)
            int cnt = rem - g;
            int jj = (j8 < cnt) ? j8 : 0;
            int sg = __shfl(sl, g + jj, 64);
            float w = (j8 < cnt) ? __expf(lrelu(apf[sg * 8 + fidx] + dn)) : 0.f;
            wsum += w;
            for (int j2 = 0; j2 < cnt; ++j2) {
                int s = __builtin_amdgcn_readlane(sl, g + j2);
                float wa = __shfl(w, j2 * 8 + hA, 64);
                float wb = __shfl(w, j2 * 8 + hA + 4, 64);
                float2 gg = __half22float2(h2p[s * 64 + l]);
                accA = fmaf(wa, gg.x, accA);
                accB = fmaf(wb, gg.y, accB);
            }
        }
    }
    // den[h] = sum over edge slots (lanes h, h+8, ..., h+56)
    wsum += __shfl_xor(wsum, 8, 64);
    wsum += __shfl_xor(wsum, 16, 64);
    wsum += __shfl_xor(wsum, 32, 64);
    float denA = denTA + __shfl(wsum, hA, 64);
    float denB = denTB + __shfl(wsum, hA + 4, 64);

    float v = accA / denA + accB / denB;
    v += __shfl_xor(v, 16, 64);
    v += __shfl_xor(v, 32, 64);
    v *= 0.125f;  // mean over 8 heads
    if (l < 16) smv[wid][l] = v;
    if (l == 0) smg[wid] = batch[n];
    __syncthreads();
    if (t < 64) {
        int w = t >> 4, c = t & 15;
        int g = smg[w];
        bool leader = true;
        for (int w2 = 0; w2 < w; ++w2)
            if (smg[w2] == g) { leader = false; break; }
        if (leader) {
            float s = smv[w][c];
            for (int w2 = w + 1; w2 < 4; ++w2)
                if (smg[w2] == g) s += smv[w2][c];
            atomicAdd(&pool[g * 16 + c], s);
        }
    }
}

// ---- final: pooled mean (+b2) @ Wfc + bfc -> [64,4]
__global__ void k_final(const float* __restrict__ pool, const int* __restrict__ cnt,
                        const float* __restrict__ b2, const float* __restrict__ Wfc,
                        const float* __restrict__ bfc, float* __restrict__ out) {
    int t = threadIdx.x;
    int g = t >> 2, k = t & 3;
    float c = (float)(cnt[g] > 0 ? cnt[g] : 1);
    float acc = bfc[k];
#pragma unroll
    for (int ci = 0; ci < 16; ++ci)
        acc += (pool[g * 16 + ci] / c + b2[ci]) * Wfc[ci * 4 + k];
    out[g * 4 + k] = acc;
}

extern "C" void kernel_launch(void* const* d_in, const int* in_sizes, int n_in,
                              void* d_out, int out_size, void* d_ws, size_t ws_size,
                              hipStream_t stream) {
    const float* x   = (const float*)d_in[0];
    const float* W1  = (const float*)d_in[1];
    const float* as1 = (const float*)d_in[2];
    const float* ad1 = (const float*)d_in[3];
    const float* b1  = (const float*)d_in[4];
    const float* W2  = (const float*)d_in[5];
    const float* as2 = (const float*)d_in[6];
    const float* ad2 = (const float*)d_in[7];
    const float* b2  = (const float*)d_in[8];
    const float* Wfc = (const float*)d_in[9];
    const float* bfc = (const float*)d_in[10];
    const int* ei    = (const int*)d_in[11];
    const int* batch = (const int*)d_in[12];
    const int* srcv  = ei;             // edge_index[0]
    const int* dstv  = ei + N_EDGES;   // edge_index[1]

    char* ws = (char*)d_ws;
    size_t o = 0;
    auto alloc = [&](size_t bytes) {
        void* p = ws + o;
        o += (bytes + 255) & ~(size_t)255;
        return p;
    };
    // zero-region first (one memset): cnt, pool, gbin_cursor
    int*    cnt     = (int*)alloc(64 * 4);
    float*  pool    = (float*)alloc(64 * 16 * 4);
    int*    gbin    = (int*)alloc(NBIN * 4);
    size_t  zbytes  = o;
    int*    off     = (int*)alloc((size_t)(N_NODES + 1) * 4);
    int*    csr     = (int*)alloc((size_t)N_EDGES * 4);
    // union region: binned (CSR build only) aliases h2p/ap/dp (l1gemm onward)
    char*   ubase   = (char*)alloc((size_t)N_NODES * 64 * 4 + (size_t)N_NODES * 4 * 8 * 2);
    int2*   binned  = (int2*)ubase;
    __half2* h2p    = (__half2*)ubase;
    float2* ap      = (float2*)(ubase + (size_t)N_NODES * 64 * 4);
    float2* dp      = (float2*)(ubase + (size_t)N_NODES * 64 * 4 + (size_t)N_NODES * 4 * 8);

    hipMemsetAsync(d_ws, 0, zbytes, stream);

    int nbA = (N_EDGES + EPB - 1) / EPB;   // 782

    k_binA<<<nbA, 512, 0, stream>>>(srcv, dstv, batch, gbin, cnt, binned);
    k_binB<<<NBIN, 1024, 0, stream>>>(binned, gbin, off, csr);
    k_l1gemm<<<N_NODES / 32, 256, 0, stream>>>(x, W1, as1, ad1, b1, W2, as2, ad2,
                                               off, csr, h2p, ap, dp);
    k_layer2<<<N_NODES / 4, 256, 0, stream>>>(h2p, ap, dp, off, csr, batch, pool);
    k_final<<<1, 256, 0, stream>>>(pool, cnt, b2, Wfc, bfc, (float*)d_out);
}